// Round 15
// baseline (301.437 us; speedup 1.0000x reference)
//
#include <hip/hip_runtime.h>

// FCPlanenet on MI355X (gfx950). fp32 inputs, fp32 output [32*9].
// Round 15: (1) MFMA-ized pos-encode on R13's best layer0 shape (no LDS
// staging): q = p@Wpos+bpos via 16x16x32 MFMA with K=4 active (x,y,z,bias).
// Encode-weight columns permuted by phi(m) so the MFMA D output lands
// exactly in main-MFMA A-frag layout: af[ks].us[j] = relu(qe[2ks+(j>>2)][j&3])
// == e[c][ks*32+g*8+j]  (derived from the R10-verified D map; register-local).
// (2) combine fused into k_layer (redundant per-block rm+cv) + ping-pong pm.
// 6 dispatches total. Middle k_layer = R14's verified body.

using bf16x8 = __attribute__((ext_vector_type(8))) __bf16;
using u16x8  = __attribute__((ext_vector_type(8))) unsigned short;
using f32x4  = __attribute__((ext_vector_type(4))) float;

__device__ __forceinline__ unsigned short f2bf(float x) {
  __bf16 b = (__bf16)x;
  return __builtin_bit_cast(unsigned short, b);
}

__device__ __forceinline__ f32x4 mfma16(bf16x8 a, bf16x8 b, f32x4 c) {
  return __builtin_amdgcn_mfma_f32_16x16x32_bf16(a, b, c, 0, 0, 0);
}

union FragU { unsigned short us[8]; u16x8 u; bf16x8 v; };

// ---------------------------------------------------------------------------
// Pack all four W (fp32 KxN, N=128) -> frag-ordered bf16 (original k order).
// slot = (ks*8 + nt)*64 + lane ; holds W[ks*32+(lane>>4)*8+j][nt*16+(lane&15)]
// ---------------------------------------------------------------------------
__global__ __launch_bounds__(256) void k_pack_all(
    const float* __restrict__ W0, const float* __restrict__ W1,
    const float* __restrict__ W2, const float* __restrict__ W3,
    unsigned short* __restrict__ Wt) {
  const int blk = blockIdx.x, t = threadIdx.x;
  const float* src; int slot; unsigned short* dst;
  if (blk < 16)      { src = W0; slot = blk * 256 + t;        dst = Wt; }
  else if (blk < 24) { src = W1; slot = (blk - 16) * 256 + t; dst = Wt + 32768; }
  else if (blk < 32) { src = W2; slot = (blk - 24) * 256 + t; dst = Wt + 49152; }
  else               { src = W3; slot = (blk - 32) * 256 + t; dst = Wt + 65536; }
  const int ks = slot >> 9, rem = slot & 511;
  const int nt = rem >> 6, lane = rem & 63;
  const int n = nt * 16 + (lane & 15);
  const int kb = ks * 32 + ((lane >> 4) << 3);
  FragU fr;
#pragma unroll
  for (int j = 0; j < 8; ++j) fr.us[j] = f2bf(src[(kb + j) * 128 + n]);
  reinterpret_cast<u16x8*>(dst)[slot] = fr.u;
}

// ---------------------------------------------------------------------------
// Layer 0: 64 rows/block, 4 waves (2 rowg x 2 colg). MFMA encode (K=4),
// register repack, main MFMA, register-direct epilogue. No A-staging LDS.
// ---------------------------------------------------------------------------
__global__ __launch_bounds__(256) void k_layer0(
    const float* __restrict__ p, const float* __restrict__ Wpos,
    const float* __restrict__ bpos, const float* __restrict__ b0,
    const unsigned short* __restrict__ Wt0, unsigned short* __restrict__ h,
    float* __restrict__ pm) {
  __shared__ unsigned short wlsb[1024];   // 2 KB: per packed col m: {Wx,Wy,Wz,b}
  __shared__ float pmaxs[2][128];
  const int t = threadIdx.x, blk = blockIdx.x;

  // Build permuted encode-weight table: col m holds original feature phi(m).
  {
    const int m = t;
    const int phi = ((m >> 4) >> 1) * 32 + (((m & 15) >> 2) << 3) +
                    (((m >> 4) & 1) << 2) + (m & 3);
    ushort4 wv;
    wv.x = f2bf(Wpos[phi]);       wv.y = f2bf(Wpos[256 + phi]);
    wv.z = f2bf(Wpos[512 + phi]); wv.w = f2bf(bpos[phi]);
    *reinterpret_cast<ushort4*>(&wlsb[m * 4]) = wv;
  }
  __syncthreads();

  const int w = t >> 6, lane = t & 63, g = lane >> 4, c = lane & 15;
  const int rowg = w >> 1, colg = w & 1;

  // p-side fragments (B operand): k=0..3 = (px,py,pz,1) at g==0 lanes.
  FragU pf[2];
#pragma unroll
  for (int mi = 0; mi < 2; ++mi) {
#pragma unroll
    for (int j = 0; j < 8; ++j) pf[mi].us[j] = 0;
    const int row = blk * 64 + rowg * 32 + mi * 16 + c;
    if (g == 0) {
      pf[mi].us[0] = f2bf(p[row * 3 + 0]);
      pf[mi].us[1] = f2bf(p[row * 3 + 1]);
      pf[mi].us[2] = f2bf(p[row * 3 + 2]);
      pf[mi].us[3] = (unsigned short)0x3F80;   // 1.0 (bias multiplier)
    }
  }

  // Encode via MFMA + register repack into main-loop A-frags.
  FragU af[2][8];
#pragma unroll
  for (int mi = 0; mi < 2; ++mi) {
    f32x4 qe[16];
#pragma unroll
    for (int nt = 0; nt < 16; ++nt) {
      FragU a1;
#pragma unroll
      for (int j = 0; j < 8; ++j) a1.us[j] = 0;
      if (g == 0) {
        const ushort4 wv = *reinterpret_cast<const ushort4*>(&wlsb[(nt * 16 + c) * 4]);
        a1.us[0] = wv.x; a1.us[1] = wv.y; a1.us[2] = wv.z; a1.us[3] = wv.w;
      }
      qe[nt] = mfma16(a1.v, pf[mi].v, f32x4{0.f, 0.f, 0.f, 0.f});
    }
#pragma unroll
    for (int ks = 0; ks < 8; ++ks)
#pragma unroll
      for (int j = 0; j < 8; ++j)
        af[mi][ks].us[j] = f2bf(fmaxf(qe[ks * 2 + (j >> 2)][j & 3], 0.f));
  }

  // Main MFMA loop (R13 structure): wave 32 rows x 64 cols, B from global.
  f32x4 acc[2][4];
#pragma unroll
  for (int mi = 0; mi < 2; ++mi)
#pragma unroll
    for (int ntl = 0; ntl < 4; ++ntl) acc[mi][ntl] = f32x4{0.f, 0.f, 0.f, 0.f};

  const bf16x8* Bf = reinterpret_cast<const bf16x8*>(Wt0);
#pragma unroll
  for (int ks = 0; ks < 8; ++ks) {
#pragma unroll
    for (int ntl = 0; ntl < 4; ++ntl) {
      const bf16x8 B = Bf[(ks * 8 + colg * 4 + ntl) * 64 + lane];
      acc[0][ntl] = mfma16(B, af[0][ks].v, acc[0][ntl]);
      acc[1][ntl] = mfma16(B, af[1][ks].v, acc[1][ntl]);
    }
  }

  // Register-direct epilogue (R13-verified).
  unsigned short* hout = h + (size_t)blk * 8192;
#pragma unroll
  for (int ntl = 0; ntl < 4; ++ntl) {
    const int ntg = colg * 4 + ntl;
    const float4 bb = *reinterpret_cast<const float4*>(&b0[ntg * 16 + g * 4]);
    float vm[4] = {0.f, 0.f, 0.f, 0.f};
#pragma unroll
    for (int mi = 0; mi < 2; ++mi) {
      const float v0 = fmaxf(acc[mi][ntl][0] + bb.x, 0.f);
      const float v1 = fmaxf(acc[mi][ntl][1] + bb.y, 0.f);
      const float v2 = fmaxf(acc[mi][ntl][2] + bb.z, 0.f);
      const float v3 = fmaxf(acc[mi][ntl][3] + bb.w, 0.f);
      vm[0] = fmaxf(vm[0], v0); vm[1] = fmaxf(vm[1], v1);
      vm[2] = fmaxf(vm[2], v2); vm[3] = fmaxf(vm[3], v3);
      ushort4 s4;
      s4.x = f2bf(v0); s4.y = f2bf(v1); s4.z = f2bf(v2); s4.w = f2bf(v3);
      const int slot = (rowg * 2 + mi) * 256 + (ntg >> 1) * 64 +
                       ((ntg & 1) * 2 + (g >> 1)) * 16 + c;
      *reinterpret_cast<ushort4*>(&hout[slot * 8 + (g & 1) * 4]) = s4;
    }
#pragma unroll
    for (int r = 0; r < 4; ++r) {
      vm[r] = fmaxf(vm[r], __shfl_xor(vm[r], 1, 64));
      vm[r] = fmaxf(vm[r], __shfl_xor(vm[r], 2, 64));
      vm[r] = fmaxf(vm[r], __shfl_xor(vm[r], 4, 64));
      vm[r] = fmaxf(vm[r], __shfl_xor(vm[r], 8, 64));
    }
    if (c == 0) {
#pragma unroll
      for (int r = 0; r < 4; ++r) pmaxs[rowg][ntg * 16 + g * 4 + r] = vm[r];
    }
  }
  __syncthreads();
  if (t < 128) pm[(size_t)blk * 128 + t] = fmaxf(pmaxs[0][t], pmaxs[1][t]);
}

// ---------------------------------------------------------------------------
// Pooled layer with FUSED combine: each block computes rm+cv from pm partials
// (redundantly, ~1us overlapped), then h = relu(h@Wa + cv) (128 rows/block,
// R14-verified body), pm partials -> pmout (ping-pong buffer).
// ---------------------------------------------------------------------------
__global__ __launch_bounds__(256) void k_layer(
    const unsigned short* __restrict__ Wta, const float* __restrict__ Wn,
    const float* __restrict__ bn, const float* __restrict__ pmin, int nper,
    unsigned short* __restrict__ h, float* __restrict__ pmout, int write_h) {
  __shared__ float part[2][128];
  __shared__ float rm[128];
  __shared__ float cvv[128];
  __shared__ float pmaxs[2][128];
  const int t = threadIdx.x, blk = blockIdx.x;
  const int w = t >> 6, lane = t & 63, g = lane >> 4, c = lane & 15;
  const int rowg = w >> 1, colg = w & 1;
  const int b = blk >> 6;   // 64 blocks (of 128 rows) per batch of 8192
  const int f = t & 127, half = t >> 7, hn = nper >> 1;

  // fused combine: m = max over nper partials; cv = relu(m)@Wn[128:256]+bn
  float m = 0.f;
  for (int i = half * hn; i < half * hn + hn; ++i)
    m = fmaxf(m, pmin[(size_t)(b * nper + i) * 128 + f]);
  part[half][f] = m;
  __syncthreads();
  if (t < 128) rm[f] = fmaxf(part[0][f], part[1][f]);
  __syncthreads();
  float s = 0.f;
  for (int q = half * 64; q < half * 64 + 64; ++q)
    s += rm[q] * Wn[(128 + q) * 128 + f];
  part[half][f] = s;
  __syncthreads();
  if (t < 128) cvv[f] = part[0][f] + part[1][f] + bn[f];
  __syncthreads();

  // main loop (R14-verified): wave 64 rows x 64 cols, acc[4][4], 4:1 B reuse
  f32x4 acc[4][4];
#pragma unroll
  for (int mi = 0; mi < 4; ++mi)
#pragma unroll
    for (int ntl = 0; ntl < 4; ++ntl) acc[mi][ntl] = f32x4{0.f, 0.f, 0.f, 0.f};

  const u16x8* hblk = reinterpret_cast<const u16x8*>(h) + (size_t)blk * 2048;
  const bf16x8* Bf = reinterpret_cast<const bf16x8*>(Wta);
#pragma unroll
  for (int ks = 0; ks < 4; ++ks) {
    bf16x8 B[4];
#pragma unroll
    for (int ntl = 0; ntl < 4; ++ntl)
      B[ntl] = Bf[(ks * 8 + colg * 4 + ntl) * 64 + lane];
    FragU a[4];
#pragma unroll
    for (int mi = 0; mi < 4; ++mi)
      a[mi].u = hblk[(rowg * 4 + mi) * 256 + ks * 64 + lane];
#pragma unroll
    for (int mi = 0; mi < 4; ++mi)
#pragma unroll
      for (int ntl = 0; ntl < 4; ++ntl)
        acc[mi][ntl] = mfma16(B[ntl], a[mi].v, acc[mi][ntl]);
  }

  // epilogue (R14-verified)
  unsigned short* hout = h + (size_t)blk * 16384;
#pragma unroll
  for (int ntl = 0; ntl < 4; ++ntl) {
    const int ntg = colg * 4 + ntl;
    const float4 bb = *reinterpret_cast<const float4*>(&cvv[ntg * 16 + g * 4]);
    float vm[4] = {0.f, 0.f, 0.f, 0.f};
#pragma unroll
    for (int mi = 0; mi < 4; ++mi) {
      const float v0 = fmaxf(acc[mi][ntl][0] + bb.x, 0.f);
      const float v1 = fmaxf(acc[mi][ntl][1] + bb.y, 0.f);
      const float v2 = fmaxf(acc[mi][ntl][2] + bb.z, 0.f);
      const float v3 = fmaxf(acc[mi][ntl][3] + bb.w, 0.f);
      vm[0] = fmaxf(vm[0], v0); vm[1] = fmaxf(vm[1], v1);
      vm[2] = fmaxf(vm[2], v2); vm[3] = fmaxf(vm[3], v3);
      if (write_h) {
        ushort4 s4;
        s4.x = f2bf(v0); s4.y = f2bf(v1); s4.z = f2bf(v2); s4.w = f2bf(v3);
        const int slot = (rowg * 4 + mi) * 256 + (ntg >> 1) * 64 +
                         ((ntg & 1) * 2 + (g >> 1)) * 16 + c;
        *reinterpret_cast<ushort4*>(&hout[slot * 8 + (g & 1) * 4]) = s4;
      }
    }
#pragma unroll
    for (int r = 0; r < 4; ++r) {
      vm[r] = fmaxf(vm[r], __shfl_xor(vm[r], 1, 64));
      vm[r] = fmaxf(vm[r], __shfl_xor(vm[r], 2, 64));
      vm[r] = fmaxf(vm[r], __shfl_xor(vm[r], 4, 64));
      vm[r] = fmaxf(vm[r], __shfl_xor(vm[r], 8, 64));
    }
    if (c == 0) {
#pragma unroll
      for (int r = 0; r < 4; ++r) pmaxs[rowg][ntg * 16 + g * 4 + r] = vm[r];
    }
  }
  __syncthreads();
  if (t < 128) pmout[(size_t)blk * 128 + t] = fmaxf(pmaxs[0][t], pmaxs[1][t]);
}

// ---------------------------------------------------------------------------
// Final: g = max over nper partials; 5-layer head MLP (fp32); out fp32 [32,9]
// ---------------------------------------------------------------------------
__global__ __launch_bounds__(256) void k_final(
    const float* __restrict__ pm3, int nper,
    const float* __restrict__ Wc,  const float* __restrict__ bc,
    const float* __restrict__ Wm0, const float* __restrict__ bm0,
    const float* __restrict__ Wm1, const float* __restrict__ bm1,
    const float* __restrict__ Wm2, const float* __restrict__ bm2,
    const float* __restrict__ Wp,  const float* __restrict__ bp,
    float* __restrict__ out) {
  const int b = blockIdx.x, t = threadIdx.x;
  const int f = t & 127, half = t >> 7;
  __shared__ float part[2][128];
  __shared__ float x[128];
  const int hn = nper >> 1;
  float m = 0.f;
  for (int i = half * hn; i < half * hn + hn; ++i)
    m = fmaxf(m, pm3[(size_t)(b * nper + i) * 128 + f]);
  part[half][f] = m;
  __syncthreads();
  if (t < 128) x[f] = fmaxf(part[0][f], part[1][f]);
  __syncthreads();

  const float* Ws[4] = {Wc, Wm0, Wm1, Wm2};
  const float* bs[4] = {bc, bm0, bm1, bm2};
#pragma unroll
  for (int L = 0; L < 4; ++L) {
    float s = 0.f;
    for (int q = half * 64; q < half * 64 + 64; ++q)
      s += x[q] * Ws[L][q * 128 + f];
    part[half][f] = s;
    __syncthreads();
    if (t < 128) x[f] = fmaxf(part[0][f] + part[1][f] + bs[L][f], 0.f);
    __syncthreads();
  }
  if (t < 9) {
    float s = bp[t];
    for (int q = 0; q < 128; ++q) s += x[q] * Wp[q * 9 + t];
    out[b * 9 + t] = s;
  }
}

// ---------------------------------------------------------------------------
extern "C" void kernel_launch(void* const* d_in, const int* in_sizes, int n_in,
                              void* d_out, int out_size, void* d_ws, size_t ws_size,
                              hipStream_t stream) {
  const float *p = nullptr, *Wpos = nullptr, *bpos = nullptr;
  const float *Wp = nullptr, *bp = nullptr;
  const float *W256[4] = {}; int nW256 = 0;
  const float *W128[4] = {}; int nW128 = 0;
  const float *B128[8] = {}; int nB128 = 0;
  for (int i = 0; i < n_in; ++i) {
    const float* q = (const float*)d_in[i];
    switch (in_sizes[i]) {
      case 786432: p = q; break;
      case 768:    Wpos = q; break;
      case 256:    bpos = q; break;
      case 1152:   Wp = q; break;
      case 9:      bp = q; break;
      case 32768:  if (nW256 < 4) W256[nW256++] = q; break;
      case 16384:  if (nW128 < 4) W128[nW128++] = q; break;
      case 128:    if (nB128 < 8) B128[nB128++] = q; break;
      default: break;
    }
  }
  const float *W0 = W256[0], *W1 = W256[1], *W2 = W256[2], *W3 = W256[3];
  const float *Wc = W128[0], *Wm0 = W128[1], *Wm1 = W128[2], *Wm2 = W128[3];
  const float *b0 = B128[0], *b1 = B128[1], *b2 = B128[2], *b3 = B128[3];
  const float *bc = B128[4], *bm0 = B128[5], *bm1 = B128[6], *bm2 = B128[7];
  float* out = (float*)d_out;

  // ws layout (~67.2 MB)
  char* ws = (char*)d_ws;
  float* pm0 = (float*)ws;                                         // 2 MiB
  float* pm1 = (float*)(ws + 2097152);                             // 1 MiB
  unsigned short* Wt = (unsigned short*)(ws + 3145728);            // 160 KiB
  unsigned short* Wt0 = Wt;
  unsigned short* Wt1 = Wt + 32768;
  unsigned short* Wt2 = Wt + 49152;
  unsigned short* Wt3 = Wt + 65536;
  unsigned short* h = Wt + 81920;                                  // 64 MiB

  k_pack_all<<<40, 256, 0, stream>>>(W0, W1, W2, W3, Wt);
  k_layer0<<<4096, 256, 0, stream>>>(p, Wpos, bpos, b0, Wt0, h, pm0);
  k_layer<<<2048, 256, 0, stream>>>(Wt1, W1, b1, pm0, 128, h, pm1, 1);
  k_layer<<<2048, 256, 0, stream>>>(Wt2, W2, b2, pm1, 64, h, pm0, 1);
  k_layer<<<2048, 256, 0, stream>>>(Wt3, W3, b3, pm0, 64, h, pm1, 0);
  k_final<<<32, 256, 0, stream>>>(pm1, 64, Wc, bc, Wm0, bm0, Wm1, bm1, Wm2, bm2, Wp, bp, out);
}

// Round 16
// 179.896 us; speedup vs baseline: 1.6756x; 1.6756x over previous
//
#include <hip/hip_runtime.h>

// FCPlanenet on MI355X (gfx950). fp32 inputs, fp32 output [32*9].
// Round 16: layer0 = R13 shape + MFMA-encode (R15-verified algebra, phi-
// permuted weight table) but INTERLEAVED per-ks so only qe0/qe1/af are live
// (R15 kept qe[16]+af[2][8] resident -> VGPR 140, occ 10.7%, 105us).
// Mids: R14's verified 128-row k_layer + separate k_combine (R15's fused
// combine serialized a 64-iter reduce per block: rest-of-pipe 128->196us).
// h layout (verified R6+): slot[tl*256+ks*64+g'*16+c] = row tl*16+c,
//   feats ks*32+g'*8..+7 (u16x8). Swapped-MFMA D map: col=c, feats g*4+r.

using bf16x8 = __attribute__((ext_vector_type(8))) __bf16;
using u16x8  = __attribute__((ext_vector_type(8))) unsigned short;
using f32x4  = __attribute__((ext_vector_type(4))) float;

__device__ __forceinline__ unsigned short f2bf(float x) {
  __bf16 b = (__bf16)x;
  return __builtin_bit_cast(unsigned short, b);
}

__device__ __forceinline__ f32x4 mfma16(bf16x8 a, bf16x8 b, f32x4 c) {
  return __builtin_amdgcn_mfma_f32_16x16x32_bf16(a, b, c, 0, 0, 0);
}

union FragU { unsigned short us[8]; u16x8 u; bf16x8 v; };

// ---------------------------------------------------------------------------
// Pack all four W (fp32 KxN, N=128) -> frag-ordered bf16.
// slot = (ks*8 + nt)*64 + lane ; holds W[ks*32+(lane>>4)*8+j][nt*16+(lane&15)]
// ---------------------------------------------------------------------------
__global__ __launch_bounds__(256) void k_pack_all(
    const float* __restrict__ W0, const float* __restrict__ W1,
    const float* __restrict__ W2, const float* __restrict__ W3,
    unsigned short* __restrict__ Wt) {
  const int blk = blockIdx.x, t = threadIdx.x;
  const float* src; int slot; unsigned short* dst;
  if (blk < 16)      { src = W0; slot = blk * 256 + t;        dst = Wt; }
  else if (blk < 24) { src = W1; slot = (blk - 16) * 256 + t; dst = Wt + 32768; }
  else if (blk < 32) { src = W2; slot = (blk - 24) * 256 + t; dst = Wt + 49152; }
  else               { src = W3; slot = (blk - 32) * 256 + t; dst = Wt + 65536; }
  const int ks = slot >> 9, rem = slot & 511;
  const int nt = rem >> 6, lane = rem & 63;
  const int n = nt * 16 + (lane & 15);
  const int kb = ks * 32 + ((lane >> 4) << 3);
  FragU fr;
#pragma unroll
  for (int j = 0; j < 8; ++j) fr.us[j] = f2bf(src[(kb + j) * 128 + n]);
  reinterpret_cast<u16x8*>(dst)[slot] = fr.u;
}

// ---------------------------------------------------------------------------
// Layer 0: 64 rows/block, 4 waves (2 rowg x 2 colg). Interleaved MFMA encode:
// per ks { 2 encode MFMAs (K=4: x,y,z,bias) -> relu+pack -> 4 main MFMAs }.
// phi-permuted encode table (R15-verified): af.us[j] = relu(qe[j>>2][j&3])
// lands exactly in main-MFMA A-frag layout.
// ---------------------------------------------------------------------------
__global__ __launch_bounds__(256) void k_layer0(
    const float* __restrict__ p, const float* __restrict__ Wpos,
    const float* __restrict__ bpos, const float* __restrict__ b0,
    const unsigned short* __restrict__ Wt0, unsigned short* __restrict__ h,
    float* __restrict__ pm) {
  __shared__ unsigned short wlsb[1024];   // 2 KB: packed col m -> {Wx,Wy,Wz,b}
  __shared__ float pmaxs[2][128];
  const int t = threadIdx.x, blk = blockIdx.x;

  {  // permuted encode-weight table (phi verified R15)
    const int m = t;
    const int phi = ((m >> 4) >> 1) * 32 + (((m & 15) >> 2) << 3) +
                    (((m >> 4) & 1) << 2) + (m & 3);
    ushort4 wv;
    wv.x = f2bf(Wpos[phi]);       wv.y = f2bf(Wpos[256 + phi]);
    wv.z = f2bf(Wpos[512 + phi]); wv.w = f2bf(bpos[phi]);
    *reinterpret_cast<ushort4*>(&wlsb[m * 4]) = wv;
  }
  __syncthreads();

  const int w = t >> 6, lane = t & 63, g = lane >> 4, c = lane & 15;
  const int rowg = w >> 1, colg = w & 1;

  // p-side fragments (B operand): k=0..3 = (px,py,pz,1) at g==0 lanes.
  FragU pf[2];
#pragma unroll
  for (int mi = 0; mi < 2; ++mi) {
#pragma unroll
    for (int j = 0; j < 8; ++j) pf[mi].us[j] = 0;
    if (g == 0) {
      const int row = blk * 64 + rowg * 32 + mi * 16 + c;
      pf[mi].us[0] = f2bf(p[row * 3 + 0]);
      pf[mi].us[1] = f2bf(p[row * 3 + 1]);
      pf[mi].us[2] = f2bf(p[row * 3 + 2]);
      pf[mi].us[3] = (unsigned short)0x3F80;   // 1.0 (bias lane)
    }
  }

  f32x4 acc[2][4];
#pragma unroll
  for (int mi = 0; mi < 2; ++mi)
#pragma unroll
    for (int ntl = 0; ntl < 4; ++ntl) acc[mi][ntl] = f32x4{0.f, 0.f, 0.f, 0.f};

  const bf16x8* Bf = reinterpret_cast<const bf16x8*>(Wt0);
  const f32x4 zz = {0.f, 0.f, 0.f, 0.f};

#pragma unroll
  for (int ks = 0; ks < 8; ++ks) {
    // B panel for this ks (global, L2-resident)
    bf16x8 B[4];
#pragma unroll
    for (int ntl = 0; ntl < 4; ++ntl)
      B[ntl] = Bf[(ks * 8 + colg * 4 + ntl) * 64 + lane];

    // encode-weight frags for nt = 2ks, 2ks+1 (K=4 active at g==0)
    FragU a1_0, a1_1;
#pragma unroll
    for (int j = 0; j < 8; ++j) { a1_0.us[j] = 0; a1_1.us[j] = 0; }
    if (g == 0) {
      const ushort4 wv0 = *reinterpret_cast<const ushort4*>(&wlsb[((2 * ks) * 16 + c) * 4]);
      const ushort4 wv1 = *reinterpret_cast<const ushort4*>(&wlsb[((2 * ks + 1) * 16 + c) * 4]);
      a1_0.us[0] = wv0.x; a1_0.us[1] = wv0.y; a1_0.us[2] = wv0.z; a1_0.us[3] = wv0.w;
      a1_1.us[0] = wv1.x; a1_1.us[1] = wv1.y; a1_1.us[2] = wv1.z; a1_1.us[3] = wv1.w;
    }

#pragma unroll
    for (int mi = 0; mi < 2; ++mi) {
      const f32x4 qe0 = mfma16(a1_0.v, pf[mi].v, zz);
      const f32x4 qe1 = mfma16(a1_1.v, pf[mi].v, zz);
      FragU af;
#pragma unroll
      for (int j = 0; j < 4; ++j) af.us[j] = f2bf(fmaxf(qe0[j], 0.f));
#pragma unroll
      for (int j = 0; j < 4; ++j) af.us[4 + j] = f2bf(fmaxf(qe1[j], 0.f));
#pragma unroll
      for (int ntl = 0; ntl < 4; ++ntl)
        acc[mi][ntl] = mfma16(B[ntl], af.v, acc[mi][ntl]);
    }
  }

  // Register-direct epilogue (R13-verified).
  unsigned short* hout = h + (size_t)blk * 8192;
#pragma unroll
  for (int ntl = 0; ntl < 4; ++ntl) {
    const int ntg = colg * 4 + ntl;
    const float4 bb = *reinterpret_cast<const float4*>(&b0[ntg * 16 + g * 4]);
    float vm[4] = {0.f, 0.f, 0.f, 0.f};
#pragma unroll
    for (int mi = 0; mi < 2; ++mi) {
      const float v0 = fmaxf(acc[mi][ntl][0] + bb.x, 0.f);
      const float v1 = fmaxf(acc[mi][ntl][1] + bb.y, 0.f);
      const float v2 = fmaxf(acc[mi][ntl][2] + bb.z, 0.f);
      const float v3 = fmaxf(acc[mi][ntl][3] + bb.w, 0.f);
      vm[0] = fmaxf(vm[0], v0); vm[1] = fmaxf(vm[1], v1);
      vm[2] = fmaxf(vm[2], v2); vm[3] = fmaxf(vm[3], v3);
      ushort4 s4;
      s4.x = f2bf(v0); s4.y = f2bf(v1); s4.z = f2bf(v2); s4.w = f2bf(v3);
      const int slot = (rowg * 2 + mi) * 256 + (ntg >> 1) * 64 +
                       ((ntg & 1) * 2 + (g >> 1)) * 16 + c;
      *reinterpret_cast<ushort4*>(&hout[slot * 8 + (g & 1) * 4]) = s4;
    }
#pragma unroll
    for (int r = 0; r < 4; ++r) {
      vm[r] = fmaxf(vm[r], __shfl_xor(vm[r], 1, 64));
      vm[r] = fmaxf(vm[r], __shfl_xor(vm[r], 2, 64));
      vm[r] = fmaxf(vm[r], __shfl_xor(vm[r], 4, 64));
      vm[r] = fmaxf(vm[r], __shfl_xor(vm[r], 8, 64));
    }
    if (c == 0) {
#pragma unroll
      for (int r = 0; r < 4; ++r) pmaxs[rowg][ntg * 16 + g * 4 + r] = vm[r];
    }
  }
  __syncthreads();
  if (t < 128) pm[(size_t)blk * 128 + t] = fmaxf(pmaxs[0][t], pmaxs[1][t]);
}

// ---------------------------------------------------------------------------
// Pooled layer (R14-verified): 128 rows/block, 4 waves, wave 64x64,
// acc[4][4], 4:1 B reuse. In-place h update, pm per block.
// ---------------------------------------------------------------------------
__global__ __launch_bounds__(256) void k_layer(
    const unsigned short* __restrict__ Wta, const float* __restrict__ cvec,
    unsigned short* __restrict__ h, float* __restrict__ pm, int write_h) {
  __shared__ float pmaxs[2][128];
  const int t = threadIdx.x, blk = blockIdx.x;
  const int w = t >> 6, lane = t & 63, g = lane >> 4, c = lane & 15;
  const int rowg = w >> 1, colg = w & 1;
  const int b = blk >> 6;   // 64 blocks (of 128 rows) per batch of 8192

  f32x4 acc[4][4];
#pragma unroll
  for (int mi = 0; mi < 4; ++mi)
#pragma unroll
    for (int ntl = 0; ntl < 4; ++ntl) acc[mi][ntl] = f32x4{0.f, 0.f, 0.f, 0.f};

  const u16x8* hblk = reinterpret_cast<const u16x8*>(h) + (size_t)blk * 2048;
  const bf16x8* Bf = reinterpret_cast<const bf16x8*>(Wta);
#pragma unroll
  for (int ks = 0; ks < 4; ++ks) {
    bf16x8 B[4];
#pragma unroll
    for (int ntl = 0; ntl < 4; ++ntl)
      B[ntl] = Bf[(ks * 8 + colg * 4 + ntl) * 64 + lane];
    FragU a[4];
#pragma unroll
    for (int mi = 0; mi < 4; ++mi)
      a[mi].u = hblk[(rowg * 4 + mi) * 256 + ks * 64 + lane];
#pragma unroll
    for (int mi = 0; mi < 4; ++mi)
#pragma unroll
      for (int ntl = 0; ntl < 4; ++ntl)
        acc[mi][ntl] = mfma16(B[ntl], a[mi].v, acc[mi][ntl]);
  }

  unsigned short* hout = h + (size_t)blk * 16384;
#pragma unroll
  for (int ntl = 0; ntl < 4; ++ntl) {
    const int ntg = colg * 4 + ntl;
    const float4 bb = *reinterpret_cast<const float4*>(&cvec[b * 128 + ntg * 16 + g * 4]);
    float vm[4] = {0.f, 0.f, 0.f, 0.f};
#pragma unroll
    for (int mi = 0; mi < 4; ++mi) {
      const float v0 = fmaxf(acc[mi][ntl][0] + bb.x, 0.f);
      const float v1 = fmaxf(acc[mi][ntl][1] + bb.y, 0.f);
      const float v2 = fmaxf(acc[mi][ntl][2] + bb.z, 0.f);
      const float v3 = fmaxf(acc[mi][ntl][3] + bb.w, 0.f);
      vm[0] = fmaxf(vm[0], v0); vm[1] = fmaxf(vm[1], v1);
      vm[2] = fmaxf(vm[2], v2); vm[3] = fmaxf(vm[3], v3);
      if (write_h) {
        ushort4 s4;
        s4.x = f2bf(v0); s4.y = f2bf(v1); s4.z = f2bf(v2); s4.w = f2bf(v3);
        const int slot = (rowg * 4 + mi) * 256 + (ntg >> 1) * 64 +
                         ((ntg & 1) * 2 + (g >> 1)) * 16 + c;
        *reinterpret_cast<ushort4*>(&hout[slot * 8 + (g & 1) * 4]) = s4;
      }
    }
#pragma unroll
    for (int r = 0; r < 4; ++r) {
      vm[r] = fmaxf(vm[r], __shfl_xor(vm[r], 1, 64));
      vm[r] = fmaxf(vm[r], __shfl_xor(vm[r], 2, 64));
      vm[r] = fmaxf(vm[r], __shfl_xor(vm[r], 4, 64));
      vm[r] = fmaxf(vm[r], __shfl_xor(vm[r], 8, 64));
    }
    if (c == 0) {
#pragma unroll
      for (int r = 0; r < 4; ++r) pmaxs[rowg][ntg * 16 + g * 4 + r] = vm[r];
    }
  }
  __syncthreads();
  if (t < 128) pm[(size_t)blk * 128 + t] = fmaxf(pmaxs[0][t], pmaxs[1][t]);
}

// ---------------------------------------------------------------------------
// Combine: m[b] = max over nper partials; c[b][n] = relu(m)@Wn[128:256] + bn
// ---------------------------------------------------------------------------
__global__ __launch_bounds__(256) void k_combine(
    const float* __restrict__ pm, const float* __restrict__ Wn,
    const float* __restrict__ bn, float* __restrict__ cout, int nper) {
  const int b = blockIdx.x, t = threadIdx.x;
  const int f = t & 127, half = t >> 7;
  __shared__ float part[2][128];
  __shared__ float rm[128];
  const int hn = nper >> 1;
  float m = 0.f;
  for (int i = half * hn; i < half * hn + hn; ++i)
    m = fmaxf(m, pm[(size_t)(b * nper + i) * 128 + f]);
  part[half][f] = m;
  __syncthreads();
  if (t < 128) rm[f] = fmaxf(part[0][f], part[1][f]);
  __syncthreads();
  float s = 0.f;
  for (int q = half * 64; q < half * 64 + 64; ++q)
    s += rm[q] * Wn[(128 + q) * 128 + f];
  part[half][f] = s;
  __syncthreads();
  if (t < 128) cout[b * 128 + f] = part[0][f] + part[1][f] + bn[f];
}

// ---------------------------------------------------------------------------
// Final: g = max over nper partials; 5-layer head MLP (fp32); out fp32 [32,9]
// ---------------------------------------------------------------------------
__global__ __launch_bounds__(256) void k_final(
    const float* __restrict__ pm3, int nper,
    const float* __restrict__ Wc,  const float* __restrict__ bc,
    const float* __restrict__ Wm0, const float* __restrict__ bm0,
    const float* __restrict__ Wm1, const float* __restrict__ bm1,
    const float* __restrict__ Wm2, const float* __restrict__ bm2,
    const float* __restrict__ Wp,  const float* __restrict__ bp,
    float* __restrict__ out) {
  const int b = blockIdx.x, t = threadIdx.x;
  const int f = t & 127, half = t >> 7;
  __shared__ float part[2][128];
  __shared__ float x[128];
  const int hn = nper >> 1;
  float m = 0.f;
  for (int i = half * hn; i < half * hn + hn; ++i)
    m = fmaxf(m, pm3[(size_t)(b * nper + i) * 128 + f]);
  part[half][f] = m;
  __syncthreads();
  if (t < 128) x[f] = fmaxf(part[0][f], part[1][f]);
  __syncthreads();

  const float* Ws[4] = {Wc, Wm0, Wm1, Wm2};
  const float* bs[4] = {bc, bm0, bm1, bm2};
#pragma unroll
  for (int L = 0; L < 4; ++L) {
    float s = 0.f;
    for (int q = half * 64; q < half * 64 + 64; ++q)
      s += x[q] * Ws[L][q * 128 + f];
    part[half][f] = s;
    __syncthreads();
    if (t < 128) x[f] = fmaxf(part[0][f] + part[1][f] + bs[L][f], 0.f);
    __syncthreads();
  }
  if (t < 9) {
    float s = bp[t];
    for (int q = 0; q < 128; ++q) s += x[q] * Wp[q * 9 + t];
    out[b * 9 + t] = s;
  }
}

// ---------------------------------------------------------------------------
extern "C" void kernel_launch(void* const* d_in, const int* in_sizes, int n_in,
                              void* d_out, int out_size, void* d_ws, size_t ws_size,
                              hipStream_t stream) {
  const float *p = nullptr, *Wpos = nullptr, *bpos = nullptr;
  const float *Wp = nullptr, *bp = nullptr;
  const float *W256[4] = {}; int nW256 = 0;
  const float *W128[4] = {}; int nW128 = 0;
  const float *B128[8] = {}; int nB128 = 0;
  for (int i = 0; i < n_in; ++i) {
    const float* q = (const float*)d_in[i];
    switch (in_sizes[i]) {
      case 786432: p = q; break;
      case 768:    Wpos = q; break;
      case 256:    bpos = q; break;
      case 1152:   Wp = q; break;
      case 9:      bp = q; break;
      case 32768:  if (nW256 < 4) W256[nW256++] = q; break;
      case 16384:  if (nW128 < 4) W128[nW128++] = q; break;
      case 128:    if (nB128 < 8) B128[nB128++] = q; break;
      default: break;
    }
  }
  const float *W0 = W256[0], *W1 = W256[1], *W2 = W256[2], *W3 = W256[3];
  const float *Wc = W128[0], *Wm0 = W128[1], *Wm1 = W128[2], *Wm2 = W128[3];
  const float *b0 = B128[0], *b1 = B128[1], *b2 = B128[2], *b3 = B128[3];
  const float *bc = B128[4], *bm0 = B128[5], *bm1 = B128[6], *bm2 = B128[7];
  float* out = (float*)d_out;

  // ws layout (~66.2 MB)
  char* ws = (char*)d_ws;
  float* pm = (float*)ws;                                          // 2 MiB
  float* cv = (float*)(ws + 2097152);                              // 16 KiB
  unsigned short* Wt = (unsigned short*)(ws + 2097152 + 16384);    // 160 KiB
  unsigned short* Wt0 = Wt;
  unsigned short* Wt1 = Wt + 32768;
  unsigned short* Wt2 = Wt + 49152;
  unsigned short* Wt3 = Wt + 65536;
  unsigned short* h = Wt + 81920;                                  // 64 MiB

  k_pack_all<<<40, 256, 0, stream>>>(W0, W1, W2, W3, Wt);
  k_layer0<<<4096, 256, 0, stream>>>(p, Wpos, bpos, b0, Wt0, h, pm);
  k_combine<<<32, 256, 0, stream>>>(pm, W1, b1, cv, 128);
  k_layer<<<2048, 256, 0, stream>>>(Wt1, cv, h, pm, 1);
  k_combine<<<32, 256, 0, stream>>>(pm, W2, b2, cv, 64);
  k_layer<<<2048, 256, 0, stream>>>(Wt2, cv, h, pm, 1);
  k_combine<<<32, 256, 0, stream>>>(pm, W3, b3, cv, 64);
  k_layer<<<2048, 256, 0, stream>>>(Wt3, cv, h, pm, 0);
  k_final<<<32, 256, 0, stream>>>(pm, 64, Wc, bc, Wm0, bm0, Wm1, bm1, Wm2, bm2, Wp, bp, out);
}

// Round 17
// 173.073 us; speedup vs baseline: 1.7417x; 1.0394x over previous
//
#include <hip/hip_runtime.h>

// FCPlanenet on MI355X (gfx950). fp32 inputs, fp32 output [32*9].
// Round 17: compose best-measured components, no new theory.
//  - k_layer0: R16 verbatim (49.4us measured) — interleaved MFMA pos-encode.
//  - k_layer:  R9 verbatim (~26us/mid measured) — 512thr/256rows, non-swapped
//    MFMA, wave-local LDS transpose epilogue, dense 16B/lane h stores.
//  - k_combine/k_final: nper-parameterized (128 after layer0, 32 after mids).
// h layout (all rounds): h[tile16][slot256] u16x8; slot[ks*64+g'*16+c] =
//   row tile*16+c... (frag order, verified R6+).

using bf16x8 = __attribute__((ext_vector_type(8))) __bf16;
using u16x8  = __attribute__((ext_vector_type(8))) unsigned short;
using f32x4  = __attribute__((ext_vector_type(4))) float;

__device__ __forceinline__ unsigned short f2bf(float x) {
  __bf16 b = (__bf16)x;
  return __builtin_bit_cast(unsigned short, b);
}

__device__ __forceinline__ f32x4 mfma16(bf16x8 a, bf16x8 b, f32x4 c) {
  return __builtin_amdgcn_mfma_f32_16x16x32_bf16(a, b, c, 0, 0, 0);
}

union FragU { unsigned short us[8]; u16x8 u; bf16x8 v; };

// ---------------------------------------------------------------------------
// Pack all four W (fp32 KxN, N=128) -> frag-ordered bf16.
// ---------------------------------------------------------------------------
__global__ __launch_bounds__(256) void k_pack_all(
    const float* __restrict__ W0, const float* __restrict__ W1,
    const float* __restrict__ W2, const float* __restrict__ W3,
    unsigned short* __restrict__ Wt) {
  const int blk = blockIdx.x, t = threadIdx.x;
  const float* src; int slot; unsigned short* dst;
  if (blk < 16)      { src = W0; slot = blk * 256 + t;        dst = Wt; }
  else if (blk < 24) { src = W1; slot = (blk - 16) * 256 + t; dst = Wt + 32768; }
  else if (blk < 32) { src = W2; slot = (blk - 24) * 256 + t; dst = Wt + 49152; }
  else               { src = W3; slot = (blk - 32) * 256 + t; dst = Wt + 65536; }
  const int ks = slot >> 9, rem = slot & 511;
  const int nt = rem >> 6, lane = rem & 63;
  const int n = nt * 16 + (lane & 15);
  const int kb = ks * 32 + ((lane >> 4) << 3);
  FragU fr;
#pragma unroll
  for (int j = 0; j < 8; ++j) fr.us[j] = f2bf(src[(kb + j) * 128 + n]);
  reinterpret_cast<u16x8*>(dst)[slot] = fr.u;
}

// ---------------------------------------------------------------------------
// Layer 0 (R16 verbatim): 64 rows/block, 4 waves. Interleaved MFMA encode.
// ---------------------------------------------------------------------------
__global__ __launch_bounds__(256) void k_layer0(
    const float* __restrict__ p, const float* __restrict__ Wpos,
    const float* __restrict__ bpos, const float* __restrict__ b0,
    const unsigned short* __restrict__ Wt0, unsigned short* __restrict__ h,
    float* __restrict__ pm) {
  __shared__ unsigned short wlsb[1024];
  __shared__ float pmaxs[2][128];
  const int t = threadIdx.x, blk = blockIdx.x;

  {  // permuted encode-weight table (phi verified R15/R16)
    const int m = t;
    const int phi = ((m >> 4) >> 1) * 32 + (((m & 15) >> 2) << 3) +
                    (((m >> 4) & 1) << 2) + (m & 3);
    ushort4 wv;
    wv.x = f2bf(Wpos[phi]);       wv.y = f2bf(Wpos[256 + phi]);
    wv.z = f2bf(Wpos[512 + phi]); wv.w = f2bf(bpos[phi]);
    *reinterpret_cast<ushort4*>(&wlsb[m * 4]) = wv;
  }
  __syncthreads();

  const int w = t >> 6, lane = t & 63, g = lane >> 4, c = lane & 15;
  const int rowg = w >> 1, colg = w & 1;

  FragU pf[2];
#pragma unroll
  for (int mi = 0; mi < 2; ++mi) {
#pragma unroll
    for (int j = 0; j < 8; ++j) pf[mi].us[j] = 0;
    if (g == 0) {
      const int row = blk * 64 + rowg * 32 + mi * 16 + c;
      pf[mi].us[0] = f2bf(p[row * 3 + 0]);
      pf[mi].us[1] = f2bf(p[row * 3 + 1]);
      pf[mi].us[2] = f2bf(p[row * 3 + 2]);
      pf[mi].us[3] = (unsigned short)0x3F80;
    }
  }

  f32x4 acc[2][4];
#pragma unroll
  for (int mi = 0; mi < 2; ++mi)
#pragma unroll
    for (int ntl = 0; ntl < 4; ++ntl) acc[mi][ntl] = f32x4{0.f, 0.f, 0.f, 0.f};

  const bf16x8* Bf = reinterpret_cast<const bf16x8*>(Wt0);
  const f32x4 zz = {0.f, 0.f, 0.f, 0.f};

#pragma unroll
  for (int ks = 0; ks < 8; ++ks) {
    bf16x8 B[4];
#pragma unroll
    for (int ntl = 0; ntl < 4; ++ntl)
      B[ntl] = Bf[(ks * 8 + colg * 4 + ntl) * 64 + lane];

    FragU a1_0, a1_1;
#pragma unroll
    for (int j = 0; j < 8; ++j) { a1_0.us[j] = 0; a1_1.us[j] = 0; }
    if (g == 0) {
      const ushort4 wv0 = *reinterpret_cast<const ushort4*>(&wlsb[((2 * ks) * 16 + c) * 4]);
      const ushort4 wv1 = *reinterpret_cast<const ushort4*>(&wlsb[((2 * ks + 1) * 16 + c) * 4]);
      a1_0.us[0] = wv0.x; a1_0.us[1] = wv0.y; a1_0.us[2] = wv0.z; a1_0.us[3] = wv0.w;
      a1_1.us[0] = wv1.x; a1_1.us[1] = wv1.y; a1_1.us[2] = wv1.z; a1_1.us[3] = wv1.w;
    }

#pragma unroll
    for (int mi = 0; mi < 2; ++mi) {
      const f32x4 qe0 = mfma16(a1_0.v, pf[mi].v, zz);
      const f32x4 qe1 = mfma16(a1_1.v, pf[mi].v, zz);
      FragU af;
#pragma unroll
      for (int j = 0; j < 4; ++j) af.us[j] = f2bf(fmaxf(qe0[j], 0.f));
#pragma unroll
      for (int j = 0; j < 4; ++j) af.us[4 + j] = f2bf(fmaxf(qe1[j], 0.f));
#pragma unroll
      for (int ntl = 0; ntl < 4; ++ntl)
        acc[mi][ntl] = mfma16(B[ntl], af.v, acc[mi][ntl]);
    }
  }

  unsigned short* hout = h + (size_t)blk * 8192;
#pragma unroll
  for (int ntl = 0; ntl < 4; ++ntl) {
    const int ntg = colg * 4 + ntl;
    const float4 bb = *reinterpret_cast<const float4*>(&b0[ntg * 16 + g * 4]);
    float vm[4] = {0.f, 0.f, 0.f, 0.f};
#pragma unroll
    for (int mi = 0; mi < 2; ++mi) {
      const float v0 = fmaxf(acc[mi][ntl][0] + bb.x, 0.f);
      const float v1 = fmaxf(acc[mi][ntl][1] + bb.y, 0.f);
      const float v2 = fmaxf(acc[mi][ntl][2] + bb.z, 0.f);
      const float v3 = fmaxf(acc[mi][ntl][3] + bb.w, 0.f);
      vm[0] = fmaxf(vm[0], v0); vm[1] = fmaxf(vm[1], v1);
      vm[2] = fmaxf(vm[2], v2); vm[3] = fmaxf(vm[3], v3);
      ushort4 s4;
      s4.x = f2bf(v0); s4.y = f2bf(v1); s4.z = f2bf(v2); s4.w = f2bf(v3);
      const int slot = (rowg * 2 + mi) * 256 + (ntg >> 1) * 64 +
                       ((ntg & 1) * 2 + (g >> 1)) * 16 + c;
      *reinterpret_cast<ushort4*>(&hout[slot * 8 + (g & 1) * 4]) = s4;
    }
#pragma unroll
    for (int r = 0; r < 4; ++r) {
      vm[r] = fmaxf(vm[r], __shfl_xor(vm[r], 1, 64));
      vm[r] = fmaxf(vm[r], __shfl_xor(vm[r], 2, 64));
      vm[r] = fmaxf(vm[r], __shfl_xor(vm[r], 4, 64));
      vm[r] = fmaxf(vm[r], __shfl_xor(vm[r], 8, 64));
    }
    if (c == 0) {
#pragma unroll
      for (int r = 0; r < 4; ++r) pmaxs[rowg][ntg * 16 + g * 4 + r] = vm[r];
    }
  }
  __syncthreads();
  if (t < 128) pm[(size_t)blk * 128 + t] = fmaxf(pmaxs[0][t], pmaxs[1][t]);
}

// ---------------------------------------------------------------------------
// Epilogue (R9 verbatim): pm from regs; wave-local LDS transpose for
// frag-order h write. hsw = this wave's 2176-u16 buffer (16 rows x 136).
// ---------------------------------------------------------------------------
__device__ __forceinline__ void epilogue512(
    unsigned short* hsw, float (*pmaxs)[128], const f32x4 (&acc)[2][8],
    const float (&bias)[8], int t, int blk, unsigned short* __restrict__ h,
    float* __restrict__ pm, bool write_h) {
  const int w = t >> 6, lane = t & 63, g = lane >> 4, c = lane & 15;
  float colmax[8];
#pragma unroll
  for (int nt = 0; nt < 8; ++nt) colmax[nt] = 0.f;

  if (write_h) {
    u16x8* hout = reinterpret_cast<u16x8*>(h) + (size_t)blk * 4096;
#pragma unroll
    for (int mi = 0; mi < 2; ++mi) {
#pragma unroll
      for (int nt = 0; nt < 8; ++nt) {
#pragma unroll
        for (int r = 0; r < 4; ++r) {
          const float v = fmaxf(acc[mi][nt][r] + bias[nt], 0.f);
          colmax[nt] = fmaxf(colmax[nt], v);
          hsw[(g * 4 + r) * 136 + nt * 16 + c] = f2bf(v);
        }
      }
#pragma unroll
      for (int s = 0; s < 4; ++s) {
        const u16x8 val =
            *reinterpret_cast<const u16x8*>(&hsw[(lane & 15) * 136 + s * 32 + 8 * g]);
        hout[(w * 2 + mi) * 256 + s * 64 + lane] = val;
      }
    }
  } else {
#pragma unroll
    for (int mi = 0; mi < 2; ++mi)
#pragma unroll
      for (int nt = 0; nt < 8; ++nt)
#pragma unroll
        for (int r = 0; r < 4; ++r)
          colmax[nt] = fmaxf(colmax[nt], acc[mi][nt][r] + bias[nt]);
  }

#pragma unroll
  for (int nt = 0; nt < 8; ++nt) {
    colmax[nt] = fmaxf(colmax[nt], __shfl_xor(colmax[nt], 16, 64));
    colmax[nt] = fmaxf(colmax[nt], __shfl_xor(colmax[nt], 32, 64));
  }
  if (lane < 16) {
#pragma unroll
    for (int nt = 0; nt < 8; ++nt) pmaxs[w][nt * 16 + c] = colmax[nt];
  }
  __syncthreads();
  if (t < 128) {
    float m = pmaxs[0][t];
#pragma unroll
    for (int i = 1; i < 8; ++i) m = fmaxf(m, pmaxs[i][t]);
    pm[(size_t)blk * 128 + t] = m;
  }
}

// ---------------------------------------------------------------------------
// Pooled layer (R9 verbatim): 256 rows/block, 8 waves, in-place.
// ---------------------------------------------------------------------------
__global__ __launch_bounds__(512, 4) void k_layer(
    const unsigned short* __restrict__ Wta, const float* __restrict__ cvec,
    unsigned short* __restrict__ h, float* __restrict__ pm, int write_h) {
  __shared__ unsigned short HS[8 * 2176];
  __shared__ float pmaxs[8][128];
  const int t = threadIdx.x, blk = blockIdx.x;
  const int w = t >> 6, lane = t & 63, c = lane & 15;
  const int b = blk >> 5;   // 32 blocks (of 256 rows) per batch of 8192

  float bias[8];
#pragma unroll
  for (int nt = 0; nt < 8; ++nt) bias[nt] = cvec[b * 128 + nt * 16 + c];

  f32x4 acc[2][8];
#pragma unroll
  for (int mi = 0; mi < 2; ++mi)
#pragma unroll
    for (int nt = 0; nt < 8; ++nt) acc[mi][nt] = f32x4{0.f, 0.f, 0.f, 0.f};

  const u16x8* hbase = reinterpret_cast<const u16x8*>(h) + (size_t)blk * 4096;
  const bf16x8* Bf = reinterpret_cast<const bf16x8*>(Wta);
#pragma unroll
  for (int ks = 0; ks < 4; ++ks) {
    FragU a0, a1;
    a0.u = hbase[(w * 2 + 0) * 256 + ks * 64 + lane];
    a1.u = hbase[(w * 2 + 1) * 256 + ks * 64 + lane];
#pragma unroll
    for (int nt = 0; nt < 8; ++nt) {
      const bf16x8 B = Bf[(ks * 8 + nt) * 64 + lane];
      acc[0][nt] = mfma16(a0.v, B, acc[0][nt]);
      acc[1][nt] = mfma16(a1.v, B, acc[1][nt]);
    }
  }
  epilogue512(&HS[w * 2176], pmaxs, acc, bias, t, blk, h, pm, write_h != 0);
}

// ---------------------------------------------------------------------------
// Combine: m[b] = max over nper partials; c[b][n] = relu(m)@Wn[128:256] + bn
// ---------------------------------------------------------------------------
__global__ __launch_bounds__(256) void k_combine(
    const float* __restrict__ pm, const float* __restrict__ Wn,
    const float* __restrict__ bn, float* __restrict__ cout, int nper) {
  const int b = blockIdx.x, t = threadIdx.x;
  const int f = t & 127, half = t >> 7;
  __shared__ float part[2][128];
  __shared__ float rm[128];
  const int hn = nper >> 1;
  float m = 0.f;
  for (int i = half * hn; i < half * hn + hn; ++i)
    m = fmaxf(m, pm[(size_t)(b * nper + i) * 128 + f]);
  part[half][f] = m;
  __syncthreads();
  if (t < 128) rm[f] = fmaxf(part[0][f], part[1][f]);
  __syncthreads();
  float s = 0.f;
  for (int q = half * 64; q < half * 64 + 64; ++q)
    s += rm[q] * Wn[(128 + q) * 128 + f];
  part[half][f] = s;
  __syncthreads();
  if (t < 128) cout[b * 128 + f] = part[0][f] + part[1][f] + bn[f];
}

// ---------------------------------------------------------------------------
// Final: g = max over nper partials; 5-layer head MLP (fp32); out fp32 [32,9]
// ---------------------------------------------------------------------------
__global__ __launch_bounds__(256) void k_final(
    const float* __restrict__ pm3, int nper,
    const float* __restrict__ Wc,  const float* __restrict__ bc,
    const float* __restrict__ Wm0, const float* __restrict__ bm0,
    const float* __restrict__ Wm1, const float* __restrict__ bm1,
    const float* __restrict__ Wm2, const float* __restrict__ bm2,
    const float* __restrict__ Wp,  const float* __restrict__ bp,
    float* __restrict__ out) {
  const int b = blockIdx.x, t = threadIdx.x;
  const int f = t & 127, half = t >> 7;
  __shared__ float part[2][128];
  __shared__ float x[128];
  const int hn = nper >> 1;
  float m = 0.f;
  for (int i = half * hn; i < half * hn + hn; ++i)
    m = fmaxf(m, pm3[(size_t)(b * nper + i) * 128 + f]);
  part[half][f] = m;
  __syncthreads();
  if (t < 128) x[f] = fmaxf(part[0][f], part[1][f]);
  __syncthreads();

  const float* Ws[4] = {Wc, Wm0, Wm1, Wm2};
  const float* bs[4] = {bc, bm0, bm1, bm2};
#pragma unroll
  for (int L = 0; L < 4; ++L) {
    float s = 0.f;
    for (int q = half * 64; q < half * 64 + 64; ++q)
      s += x[q] * Ws[L][q * 128 + f];
    part[half][f] = s;
    __syncthreads();
    if (t < 128) x[f] = fmaxf(part[0][f] + part[1][f] + bs[L][f], 0.f);
    __syncthreads();
  }
  if (t < 9) {
    float s = bp[t];
    for (int q = 0; q < 128; ++q) s += x[q] * Wp[q * 9 + t];
    out[b * 9 + t] = s;
  }
}

// ---------------------------------------------------------------------------
extern "C" void kernel_launch(void* const* d_in, const int* in_sizes, int n_in,
                              void* d_out, int out_size, void* d_ws, size_t ws_size,
                              hipStream_t stream) {
  const float *p = nullptr, *Wpos = nullptr, *bpos = nullptr;
  const float *Wp = nullptr, *bp = nullptr;
  const float *W256[4] = {}; int nW256 = 0;
  const float *W128[4] = {}; int nW128 = 0;
  const float *B128[8] = {}; int nB128 = 0;
  for (int i = 0; i < n_in; ++i) {
    const float* q = (const float*)d_in[i];
    switch (in_sizes[i]) {
      case 786432: p = q; break;
      case 768:    Wpos = q; break;
      case 256:    bpos = q; break;
      case 1152:   Wp = q; break;
      case 9:      bp = q; break;
      case 32768:  if (nW256 < 4) W256[nW256++] = q; break;
      case 16384:  if (nW128 < 4) W128[nW128++] = q; break;
      case 128:    if (nB128 < 8) B128[nB128++] = q; break;
      default: break;
    }
  }
  const float *W0 = W256[0], *W1 = W256[1], *W2 = W256[2], *W3 = W256[3];
  const float *Wc = W128[0], *Wm0 = W128[1], *Wm1 = W128[2], *Wm2 = W128[3];
  const float *b0 = B128[0], *b1 = B128[1], *b2 = B128[2], *b3 = B128[3];
  const float *bc = B128[4], *bm0 = B128[5], *bm1 = B128[6], *bm2 = B128[7];
  float* out = (float*)d_out;

  // ws layout (~66.2 MB)
  char* ws = (char*)d_ws;
  float* pm = (float*)ws;                                          // 2 MiB
  float* cv = (float*)(ws + 2097152);                              // 16 KiB
  unsigned short* Wt = (unsigned short*)(ws + 2097152 + 16384);    // 160 KiB
  unsigned short* Wt0 = Wt;
  unsigned short* Wt1 = Wt + 32768;
  unsigned short* Wt2 = Wt + 49152;
  unsigned short* Wt3 = Wt + 65536;
  unsigned short* h = Wt + 81920;                                  // 64 MiB

  k_pack_all<<<40, 256, 0, stream>>>(W0, W1, W2, W3, Wt);
  k_layer0<<<4096, 256, 0, stream>>>(p, Wpos, bpos, b0, Wt0, h, pm);
  k_combine<<<32, 256, 0, stream>>>(pm, W1, b1, cv, 128);
  k_layer<<<1024, 512, 0, stream>>>(Wt1, cv, h, pm, 1);
  k_combine<<<32, 256, 0, stream>>>(pm, W2, b2, cv, 32);
  k_layer<<<1024, 512, 0, stream>>>(Wt2, cv, h, pm, 1);
  k_combine<<<32, 256, 0, stream>>>(pm, W3, b3, cv, 32);
  k_layer<<<1024, 512, 0, stream>>>(Wt3, cv, h, pm, 0);
  k_final<<<32, 256, 0, stream>>>(pm, 32, Wc, bc, Wm0, bm0, Wm1, bm1, Wm2, bm2, Wp, bp, out);
}